// Round 1
// baseline (190.226 us; speedup 1.0000x reference)
//
#include <hip/hip_runtime.h>

#define LN_EPS 1e-5f

static __device__ __forceinline__ float4 f4zero() { return make_float4(0.f, 0.f, 0.f, 0.f); }

// ---------------------------------------------------------------------------
// K1: feat[N][32] = X[N][128] @ Wf[128][32] + bf ;  skill[N] = (int)X[n][0]
// 256 threads/block, 128-row tile, per-thread 4 rows x 4 dims register tile.
// Wf in LDS (b128 reads, conflict-free: banks 4*dg+{0..3} cover all 32).
// X read from global: per load instr only 8 distinct 16B addrs (L1 broadcast).
// ---------------------------------------------------------------------------
__global__ __launch_bounds__(256) void k_feat(
    const float* __restrict__ X, const float* __restrict__ Wf,
    const float* __restrict__ bf, float* __restrict__ feat,
    int* __restrict__ skill, int N)
{
    __shared__ float Wl[128 * 32];
    for (int i = threadIdx.x; i < 128 * 32; i += 256) Wl[i] = Wf[i];
    __syncthreads();

    const int t  = threadIdx.x;
    const int dg = t & 7;              // dims 4*dg .. 4*dg+3
    const int rg = t >> 3;             // rows 4*rg .. 4*rg+3 (rg 0..31)
    const int r0 = blockIdx.x * 128 + 4 * rg;

    const float4 bias = *(const float4*)(bf + 4 * dg);
    float4 acc[4] = {bias, bias, bias, bias};

    const float4* __restrict__ X4 = (const float4*)X;
    const float4* __restrict__ W4 = (const float4*)Wl;

    bool vld[4];
    #pragma unroll
    for (int i = 0; i < 4; ++i) vld[i] = (r0 + i) < N;

    #pragma unroll 4
    for (int f4 = 0; f4 < 32; ++f4) {
        float4 xv[4];
        #pragma unroll
        for (int i = 0; i < 4; ++i)
            xv[i] = vld[i] ? X4[(size_t)(r0 + i) * 32 + f4] : f4zero();

        if (f4 == 0 && dg == 0) {
            #pragma unroll
            for (int i = 0; i < 4; ++i)
                if (vld[i]) skill[r0 + i] = (int)xv[i].x;   // trunc-toward-zero == astype(int32)
        }

        #define K1_STEP(J, C) { \
            const float4 w = W4[(4 * f4 + (J)) * 8 + dg]; \
            _Pragma("unroll") \
            for (int i = 0; i < 4; ++i) { \
                const float xs = xv[i].C; \
                acc[i].x = fmaf(xs, w.x, acc[i].x); \
                acc[i].y = fmaf(xs, w.y, acc[i].y); \
                acc[i].z = fmaf(xs, w.z, acc[i].z); \
                acc[i].w = fmaf(xs, w.w, acc[i].w); } }
        K1_STEP(0, x) K1_STEP(1, y) K1_STEP(2, z) K1_STEP(3, w)
        #undef K1_STEP
    }

    #pragma unroll
    for (int i = 0; i < 4; ++i)
        if (vld[i]) *(float4*)(feat + (size_t)(r0 + i) * 32 + 4 * dg) = acc[i];
}

// ---------------------------------------------------------------------------
// K2: fully fused per-sample pipeline. 1 block per b (1024 blocks), 128 thr.
// Thread l (<100) owns one (b,l) row entirely in registers:
//   gather 5 feat rows -> mean+struct -> LayerNorm -> xw = hist @ Wgcn
// xw exchanged transposed via LDS xwT[32][100] (bank (4d+l)%32: conflict-free)
// for chain-GCN neighbor term + column-sum pooling; then 32x32 GEMVs for
// src_emb (pooled @ Wout) and dst_emb (feat[dst] @ Wout).
// ---------------------------------------------------------------------------
__global__ __launch_bounds__(128) void k_main(
    const float* __restrict__ feat, const int* __restrict__ skill,
    const int* __restrict__ rnodes, const int* __restrict__ ridx,
    const int* __restrict__ dst_ids,
    const float* __restrict__ w_struct, const float* __restrict__ b_struct,
    const float* __restrict__ ln_g, const float* __restrict__ ln_b,
    const float* __restrict__ Wg, const float* __restrict__ b_gcn,
    const float* __restrict__ Wo, const float* __restrict__ b_out,
    float* __restrict__ out, int B)
{
    __shared__ float Wgl[32 * 32];
    __shared__ float Wol[32 * 32];
    __shared__ float xwT[32][100];
    __shared__ float pooled[32];
    __shared__ int   pidx[5];
    __shared__ int   ivalid;
    __shared__ int   cskill;

    const int t = threadIdx.x, b = blockIdx.x;

    for (int i = t; i < 1024; i += 128) { Wgl[i] = Wg[i]; Wol[i] = Wo[i]; }
    if (t < 5)  pidx[t] = ridx[b * 5 + t];
    if (t == 5) ivalid = 0;
    if (t == 6) cskill = skill[dst_ids[b]];
    __syncthreads();

    const int l = t;
    float4 y[8];    // fused sum -> hist -> post-LN hist
    float4 xw[8];   // hist @ Wgcn -> gnn output

    if (l < 100) {
        int nodes[5];
        #pragma unroll
        for (int r = 0; r < 5; ++r) nodes[r] = rnodes[(size_t)pidx[r] * 100 + l];
        if (nodes[0] > 0) atomicAdd(&ivalid, 1);

        int simc = 0;
        #pragma unroll
        for (int r = 0; r < 5; ++r) simc += (skill[nodes[r]] == cskill) ? 1 : 0;

        #pragma unroll
        for (int c = 0; c < 8; ++c) y[c] = f4zero();
        #pragma unroll
        for (int r = 0; r < 5; ++r) {
            const float4* fp = (const float4*)(feat + (size_t)nodes[r] * 32);
            #pragma unroll
            for (int c = 0; c < 8; ++c) {
                const float4 v = fp[c];
                y[c].x += v.x; y[c].y += v.y; y[c].z += v.z; y[c].w += v.w;
            }
        }

        const float simf = (float)simc * 0.2f;
        #pragma unroll
        for (int c = 0; c < 8; ++c) {
            const float4 ws = ((const float4*)w_struct)[c];
            const float4 bs = ((const float4*)b_struct)[c];
            y[c].x = fmaf(y[c].x, 0.2f, fmaf(simf, ws.x, bs.x));
            y[c].y = fmaf(y[c].y, 0.2f, fmaf(simf, ws.y, bs.y));
            y[c].z = fmaf(y[c].z, 0.2f, fmaf(simf, ws.z, bs.z));
            y[c].w = fmaf(y[c].w, 0.2f, fmaf(simf, ws.w, bs.w));
        }

        // LayerNorm over D=32 (biased var, matches jnp.var)
        float mu = 0.f;
        #pragma unroll
        for (int c = 0; c < 8; ++c) mu += y[c].x + y[c].y + y[c].z + y[c].w;
        mu *= (1.f / 32.f);
        float var = 0.f;
        #pragma unroll
        for (int c = 0; c < 8; ++c) {
            float dx;
            dx = y[c].x - mu; var = fmaf(dx, dx, var);
            dx = y[c].y - mu; var = fmaf(dx, dx, var);
            dx = y[c].z - mu; var = fmaf(dx, dx, var);
            dx = y[c].w - mu; var = fmaf(dx, dx, var);
        }
        var *= (1.f / 32.f);
        const float rs = rsqrtf(var + LN_EPS);
        #pragma unroll
        for (int c = 0; c < 8; ++c) {
            const float4 g4 = ((const float4*)ln_g)[c];
            const float4 b4 = ((const float4*)ln_b)[c];
            y[c].x = fmaf((y[c].x - mu) * rs, g4.x, b4.x);
            y[c].y = fmaf((y[c].y - mu) * rs, g4.y, b4.y);
            y[c].z = fmaf((y[c].z - mu) * rs, g4.z, b4.z);
            y[c].w = fmaf((y[c].w - mu) * rs, g4.w, b4.w);
        }

        // xw = hist @ Wgcn  (fully unrolled: all register indices compile-time)
        #pragma unroll
        for (int c = 0; c < 8; ++c) xw[c] = f4zero();
        #define XW_ACC(D, C) { \
            const float v = y[(D) / 4].C; \
            const float4* wr = (const float4*)(Wgl + (D) * 32); \
            _Pragma("unroll") \
            for (int c = 0; c < 8; ++c) { \
                const float4 w = wr[c]; \
                xw[c].x = fmaf(v, w.x, xw[c].x); \
                xw[c].y = fmaf(v, w.y, xw[c].y); \
                xw[c].z = fmaf(v, w.z, xw[c].z); \
                xw[c].w = fmaf(v, w.w, xw[c].w); } }
        #pragma unroll
        for (int q = 0; q < 8; ++q) {
            XW_ACC(4 * q + 0, x) XW_ACC(4 * q + 1, y)
            XW_ACC(4 * q + 2, z) XW_ACC(4 * q + 3, w)
        }
        #undef XW_ACC

        // publish xw transposed for neighbor access
        #pragma unroll
        for (int q = 0; q < 8; ++q) {
            xwT[4 * q + 0][l] = xw[q].x;
            xwT[4 * q + 1][l] = xw[q].y;
            xwT[4 * q + 2][l] = xw[q].z;
            xwT[4 * q + 3][l] = xw[q].w;
        }
    }
    __syncthreads();

    // chain-GCN: out[l] = xw[l]/deg[l] + edge(l-1->l)*xw[l-1]*rsqrt(deg[l-1]deg[l]);
    // gnn = relu(out + b_gcn). deg[0]=1; deg[v>=1] = 1 + (v < valid).
    if (l < 100) {
        const int valid = ivalid;
        const bool hm = (l >= 1) && (l < valid);
        const float degl  = 1.f + ((l >= 1 && l < valid) ? 1.f : 0.f);
        const float deglm = 1.f + ((l - 1 >= 1 && (l - 1) < valid) ? 1.f : 0.f);
        const float invd  = 1.f / degl;                    // deg in {1,2}: exact
        const float invn  = hm ? rsqrtf(deglm * degl) : 0.f;
        const int lm = hm ? (l - 1) : l;                   // safe LDS index when !hm
        #define GNN_D(D, C) { \
            const float m = hm ? xwT[D][lm] * invn : 0.f; \
            const float o = fmaf(xw[(D) / 4].C, invd, m) + bg4.C; \
            xw[(D) / 4].C = fmaxf(o, 0.f); }
        #pragma unroll
        for (int q = 0; q < 8; ++q) {
            const float4 bg4 = ((const float4*)b_gcn)[q];
            GNN_D(4 * q + 0, x) GNN_D(4 * q + 1, y)
            GNN_D(4 * q + 2, z) GNN_D(4 * q + 3, w)
        }
        #undef GNN_D
    }
    __syncthreads();   // all xwT reads done before overwrite (WAR)

    if (l < 100) {
        #pragma unroll
        for (int q = 0; q < 8; ++q) {
            xwT[4 * q + 0][l] = xw[q].x;
            xwT[4 * q + 1][l] = xw[q].y;
            xwT[4 * q + 2][l] = xw[q].z;
            xwT[4 * q + 3][l] = xw[q].w;
        }
    }
    __syncthreads();

    // global_mean_pool over L=100 (column sums; banks rotate per j: conflict-free)
    if (t < 32) {
        float s = 0.f;
        for (int j = 0; j < 100; ++j) s += xwT[t][j];
        pooled[t] = s * 0.01f;
    }
    __syncthreads();

    if (t < 32) {
        float s = b_out[t];
        #pragma unroll 8
        for (int k = 0; k < 32; ++k) s = fmaf(pooled[k], Wol[k * 32 + t], s);
        out[(size_t)b * 32 + t] = s;                       // src_emb
    } else if (t < 64) {
        const int d = t - 32;
        const float* fr = feat + (size_t)dst_ids[b] * 32;  // broadcast reads
        float s = b_out[d];
        #pragma unroll 8
        for (int k = 0; k < 32; ++k) s = fmaf(fr[k], Wol[k * 32 + d], s);
        out[(size_t)B * 32 + (size_t)b * 32 + d] = s;      // dst_emb
    }
}

// ---------------------------------------------------------------------------
extern "C" void kernel_launch(void* const* d_in, const int* in_sizes, int n_in,
                              void* d_out, int out_size, void* d_ws, size_t ws_size,
                              hipStream_t stream)
{
    const float* X      = (const float*)d_in[0];   // [N,128]
    const int*   rnodes = (const int*)  d_in[1];   // [P,100]
    const int*   ridx   = (const int*)  d_in[2];   // [B,5]
    /* d_in[3] src_node_ids: unused by reference */
    const int*   dst    = (const int*)  d_in[4];   // [B]
    /* d_in[5] node_interact_times: unused */
    const float* Wf  = (const float*)d_in[6];
    const float* bf  = (const float*)d_in[7];
    const float* wst = (const float*)d_in[8];
    const float* bst = (const float*)d_in[9];
    const float* lg  = (const float*)d_in[10];
    const float* lb  = (const float*)d_in[11];
    const float* Wg  = (const float*)d_in[12];
    const float* bg  = (const float*)d_in[13];
    const float* Wo  = (const float*)d_in[14];
    const float* bo  = (const float*)d_in[15];

    const int N = in_sizes[0] / 128;   // 100000
    const int B = in_sizes[4];         // 1024

    // workspace: feat_all [N,32] f32, then skill [N] i32 (16B-aligned offsets)
    float* feat  = (float*)d_ws;
    int*   skill = (int*)((char*)d_ws + (size_t)N * 32 * sizeof(float));
    float* out   = (float*)d_out;

    k_feat<<<(N + 127) / 128, 256, 0, stream>>>(X, Wf, bf, feat, skill, N);
    k_main<<<B, 128, 0, stream>>>(feat, skill, rnodes, ridx, dst,
                                  wst, bst, lg, lb, Wg, bg, Wo, bo, out, B);
}

// Round 2
// 165.617 us; speedup vs baseline: 1.1486x; 1.1486x over previous
//
#include <hip/hip_runtime.h>

#define LN_EPS 1e-5f

static __device__ __forceinline__ float4 f4zero() { return make_float4(0.f, 0.f, 0.f, 0.f); }

// ---------------------------------------------------------------------------
// K1: feat[N][32] = X[N][128] @ Wf[128][32] + bf ;  skill[N] = (int)X[n][0]
// One thread per (row, 4-dim group): 8 threads/row, 800000 threads total
// -> 12500 waves (~48/CU requested) so HBM latency is hidden by TLP.
// Wave-level access: 8 rows x 8 dg; each X4 load instr covers 8x16B=128B
// contiguous; feat store is 1KB contiguous per wave. Wf in LDS, b128 reads
// hit banks 4*dg+{0..3} with 8-way same-address broadcast: conflict-free.
// ---------------------------------------------------------------------------
__global__ __launch_bounds__(256) void k_feat(
    const float* __restrict__ X, const float* __restrict__ Wf,
    const float* __restrict__ bf, float* __restrict__ feat,
    int* __restrict__ skill, int N)
{
    __shared__ float Wl[128 * 32];
    for (int i = threadIdx.x; i < 128 * 32; i += 256) Wl[i] = Wf[i];
    __syncthreads();

    const int gid = blockIdx.x * 256 + threadIdx.x;
    const int row = gid >> 3;          // one row per 8 threads
    const int dg  = gid & 7;           // dims 4*dg .. 4*dg+3
    if (row >= N) return;

    const float4* __restrict__ X4 = (const float4*)X + (size_t)row * 32;
    const float4* __restrict__ W4 = (const float4*)Wl;

    float4 acc = *(const float4*)(bf + 4 * dg);

    #pragma unroll 8
    for (int f4 = 0; f4 < 32; ++f4) {
        const float4 xv = X4[f4];
        if (f4 == 0 && dg == 0) skill[row] = (int)xv.x;  // trunc == astype(int32)
        const float4 w0 = W4[(4 * f4 + 0) * 8 + dg];
        const float4 w1 = W4[(4 * f4 + 1) * 8 + dg];
        const float4 w2 = W4[(4 * f4 + 2) * 8 + dg];
        const float4 w3 = W4[(4 * f4 + 3) * 8 + dg];
        acc.x = fmaf(xv.x, w0.x, acc.x);
        acc.y = fmaf(xv.x, w0.y, acc.y);
        acc.z = fmaf(xv.x, w0.z, acc.z);
        acc.w = fmaf(xv.x, w0.w, acc.w);
        acc.x = fmaf(xv.y, w1.x, acc.x);
        acc.y = fmaf(xv.y, w1.y, acc.y);
        acc.z = fmaf(xv.y, w1.z, acc.z);
        acc.w = fmaf(xv.y, w1.w, acc.w);
        acc.x = fmaf(xv.z, w2.x, acc.x);
        acc.y = fmaf(xv.z, w2.y, acc.y);
        acc.z = fmaf(xv.z, w2.z, acc.z);
        acc.w = fmaf(xv.z, w2.w, acc.w);
        acc.x = fmaf(xv.w, w3.x, acc.x);
        acc.y = fmaf(xv.w, w3.y, acc.y);
        acc.z = fmaf(xv.w, w3.z, acc.z);
        acc.w = fmaf(xv.w, w3.w, acc.w);
    }

    *(float4*)(feat + (size_t)row * 32 + 4 * dg) = acc;
}

// ---------------------------------------------------------------------------
// K2: fully fused per-sample pipeline. 1 block per b (1024 blocks), 128 thr.
// (unchanged from verified round-1 version)
// ---------------------------------------------------------------------------
__global__ __launch_bounds__(128) void k_main(
    const float* __restrict__ feat, const int* __restrict__ skill,
    const int* __restrict__ rnodes, const int* __restrict__ ridx,
    const int* __restrict__ dst_ids,
    const float* __restrict__ w_struct, const float* __restrict__ b_struct,
    const float* __restrict__ ln_g, const float* __restrict__ ln_b,
    const float* __restrict__ Wg, const float* __restrict__ b_gcn,
    const float* __restrict__ Wo, const float* __restrict__ b_out,
    float* __restrict__ out, int B)
{
    __shared__ float Wgl[32 * 32];
    __shared__ float Wol[32 * 32];
    __shared__ float xwT[32][100];
    __shared__ float pooled[32];
    __shared__ int   pidx[5];
    __shared__ int   ivalid;
    __shared__ int   cskill;

    const int t = threadIdx.x, b = blockIdx.x;

    for (int i = t; i < 1024; i += 128) { Wgl[i] = Wg[i]; Wol[i] = Wo[i]; }
    if (t < 5)  pidx[t] = ridx[b * 5 + t];
    if (t == 5) ivalid = 0;
    if (t == 6) cskill = skill[dst_ids[b]];
    __syncthreads();

    const int l = t;
    float4 y[8];    // fused sum -> hist -> post-LN hist
    float4 xw[8];   // hist @ Wgcn -> gnn output

    if (l < 100) {
        int nodes[5];
        #pragma unroll
        for (int r = 0; r < 5; ++r) nodes[r] = rnodes[(size_t)pidx[r] * 100 + l];
        if (nodes[0] > 0) atomicAdd(&ivalid, 1);

        int simc = 0;
        #pragma unroll
        for (int r = 0; r < 5; ++r) simc += (skill[nodes[r]] == cskill) ? 1 : 0;

        #pragma unroll
        for (int c = 0; c < 8; ++c) y[c] = f4zero();
        #pragma unroll
        for (int r = 0; r < 5; ++r) {
            const float4* fp = (const float4*)(feat + (size_t)nodes[r] * 32);
            #pragma unroll
            for (int c = 0; c < 8; ++c) {
                const float4 v = fp[c];
                y[c].x += v.x; y[c].y += v.y; y[c].z += v.z; y[c].w += v.w;
            }
        }

        const float simf = (float)simc * 0.2f;
        #pragma unroll
        for (int c = 0; c < 8; ++c) {
            const float4 ws = ((const float4*)w_struct)[c];
            const float4 bs = ((const float4*)b_struct)[c];
            y[c].x = fmaf(y[c].x, 0.2f, fmaf(simf, ws.x, bs.x));
            y[c].y = fmaf(y[c].y, 0.2f, fmaf(simf, ws.y, bs.y));
            y[c].z = fmaf(y[c].z, 0.2f, fmaf(simf, ws.z, bs.z));
            y[c].w = fmaf(y[c].w, 0.2f, fmaf(simf, ws.w, bs.w));
        }

        // LayerNorm over D=32 (biased var, matches jnp.var)
        float mu = 0.f;
        #pragma unroll
        for (int c = 0; c < 8; ++c) mu += y[c].x + y[c].y + y[c].z + y[c].w;
        mu *= (1.f / 32.f);
        float var = 0.f;
        #pragma unroll
        for (int c = 0; c < 8; ++c) {
            float dx;
            dx = y[c].x - mu; var = fmaf(dx, dx, var);
            dx = y[c].y - mu; var = fmaf(dx, dx, var);
            dx = y[c].z - mu; var = fmaf(dx, dx, var);
            dx = y[c].w - mu; var = fmaf(dx, dx, var);
        }
        var *= (1.f / 32.f);
        const float rs = rsqrtf(var + LN_EPS);
        #pragma unroll
        for (int c = 0; c < 8; ++c) {
            const float4 g4 = ((const float4*)ln_g)[c];
            const float4 b4 = ((const float4*)ln_b)[c];
            y[c].x = fmaf((y[c].x - mu) * rs, g4.x, b4.x);
            y[c].y = fmaf((y[c].y - mu) * rs, g4.y, b4.y);
            y[c].z = fmaf((y[c].z - mu) * rs, g4.z, b4.z);
            y[c].w = fmaf((y[c].w - mu) * rs, g4.w, b4.w);
        }

        // xw = hist @ Wgcn  (fully unrolled: all register indices compile-time)
        #pragma unroll
        for (int c = 0; c < 8; ++c) xw[c] = f4zero();
        #define XW_ACC(D, C) { \
            const float v = y[(D) / 4].C; \
            const float4* wr = (const float4*)(Wgl + (D) * 32); \
            _Pragma("unroll") \
            for (int c = 0; c < 8; ++c) { \
                const float4 w = wr[c]; \
                xw[c].x = fmaf(v, w.x, xw[c].x); \
                xw[c].y = fmaf(v, w.y, xw[c].y); \
                xw[c].z = fmaf(v, w.z, xw[c].z); \
                xw[c].w = fmaf(v, w.w, xw[c].w); } }
        #pragma unroll
        for (int q = 0; q < 8; ++q) {
            XW_ACC(4 * q + 0, x) XW_ACC(4 * q + 1, y)
            XW_ACC(4 * q + 2, z) XW_ACC(4 * q + 3, w)
        }
        #undef XW_ACC

        // publish xw transposed for neighbor access
        #pragma unroll
        for (int q = 0; q < 8; ++q) {
            xwT[4 * q + 0][l] = xw[q].x;
            xwT[4 * q + 1][l] = xw[q].y;
            xwT[4 * q + 2][l] = xw[q].z;
            xwT[4 * q + 3][l] = xw[q].w;
        }
    }
    __syncthreads();

    // chain-GCN: out[l] = xw[l]/deg[l] + edge(l-1->l)*xw[l-1]*rsqrt(deg[l-1]deg[l]);
    // gnn = relu(out + b_gcn). deg[0]=1; deg[v>=1] = 1 + (v < valid).
    if (l < 100) {
        const int valid = ivalid;
        const bool hm = (l >= 1) && (l < valid);
        const float degl  = 1.f + ((l >= 1 && l < valid) ? 1.f : 0.f);
        const float deglm = 1.f + ((l - 1 >= 1 && (l - 1) < valid) ? 1.f : 0.f);
        const float invd  = 1.f / degl;                    // deg in {1,2}: exact
        const float invn  = hm ? rsqrtf(deglm * degl) : 0.f;
        const int lm = hm ? (l - 1) : l;                   // safe LDS index when !hm
        #define GNN_D(D, C) { \
            const float m = hm ? xwT[D][lm] * invn : 0.f; \
            const float o = fmaf(xw[(D) / 4].C, invd, m) + bg4.C; \
            xw[(D) / 4].C = fmaxf(o, 0.f); }
        #pragma unroll
        for (int q = 0; q < 8; ++q) {
            const float4 bg4 = ((const float4*)b_gcn)[q];
            GNN_D(4 * q + 0, x) GNN_D(4 * q + 1, y)
            GNN_D(4 * q + 2, z) GNN_D(4 * q + 3, w)
        }
        #undef GNN_D
    }
    __syncthreads();   // all xwT reads done before overwrite (WAR)

    if (l < 100) {
        #pragma unroll
        for (int q = 0; q < 8; ++q) {
            xwT[4 * q + 0][l] = xw[q].x;
            xwT[4 * q + 1][l] = xw[q].y;
            xwT[4 * q + 2][l] = xw[q].z;
            xwT[4 * q + 3][l] = xw[q].w;
        }
    }
    __syncthreads();

    // global_mean_pool over L=100 (column sums; banks rotate per j: conflict-free)
    if (t < 32) {
        float s = 0.f;
        for (int j = 0; j < 100; ++j) s += xwT[t][j];
        pooled[t] = s * 0.01f;
    }
    __syncthreads();

    if (t < 32) {
        float s = b_out[t];
        #pragma unroll 8
        for (int k = 0; k < 32; ++k) s = fmaf(pooled[k], Wol[k * 32 + t], s);
        out[(size_t)b * 32 + t] = s;                       // src_emb
    } else if (t < 64) {
        const int d = t - 32;
        const float* fr = feat + (size_t)dst_ids[b] * 32;  // broadcast reads
        float s = b_out[d];
        #pragma unroll 8
        for (int k = 0; k < 32; ++k) s = fmaf(fr[k], Wol[k * 32 + d], s);
        out[(size_t)B * 32 + (size_t)b * 32 + d] = s;      // dst_emb
    }
}

// ---------------------------------------------------------------------------
extern "C" void kernel_launch(void* const* d_in, const int* in_sizes, int n_in,
                              void* d_out, int out_size, void* d_ws, size_t ws_size,
                              hipStream_t stream)
{
    const float* X      = (const float*)d_in[0];   // [N,128]
    const int*   rnodes = (const int*)  d_in[1];   // [P,100]
    const int*   ridx   = (const int*)  d_in[2];   // [B,5]
    /* d_in[3] src_node_ids: unused by reference */
    const int*   dst    = (const int*)  d_in[4];   // [B]
    /* d_in[5] node_interact_times: unused */
    const float* Wf  = (const float*)d_in[6];
    const float* bf  = (const float*)d_in[7];
    const float* wst = (const float*)d_in[8];
    const float* bst = (const float*)d_in[9];
    const float* lg  = (const float*)d_in[10];
    const float* lb  = (const float*)d_in[11];
    const float* Wg  = (const float*)d_in[12];
    const float* bg  = (const float*)d_in[13];
    const float* Wo  = (const float*)d_in[14];
    const float* bo  = (const float*)d_in[15];

    const int N = in_sizes[0] / 128;   // 100000
    const int B = in_sizes[4];         // 1024

    // workspace: feat_all [N,32] f32, then skill [N] i32 (16B-aligned offsets)
    float* feat  = (float*)d_ws;
    int*   skill = (int*)((char*)d_ws + (size_t)N * 32 * sizeof(float));
    float* out   = (float*)d_out;

    k_feat<<<(N * 8 + 255) / 256, 256, 0, stream>>>(X, Wf, bf, feat, skill, N);
    k_main<<<B, 128, 0, stream>>>(feat, skill, rnodes, ridx, dst,
                                  wst, bst, lg, lb, Wg, bg, Wo, bo, out, B);
}

// Round 3
// 161.517 us; speedup vs baseline: 1.1777x; 1.0254x over previous
//
#include <hip/hip_runtime.h>

#define LN_EPS 1e-5f

static __device__ __forceinline__ float4 f4zero() { return make_float4(0.f, 0.f, 0.f, 0.f); }

// ---------------------------------------------------------------------------
// K1: feat[N][32] = X[N][128] @ Wf[128][32] + bf ;  skill[N] = (int)X[n][0]
// (unchanged from verified round-2 version)
// ---------------------------------------------------------------------------
__global__ __launch_bounds__(256) void k_feat(
    const float* __restrict__ X, const float* __restrict__ Wf,
    const float* __restrict__ bf, float* __restrict__ feat,
    int* __restrict__ skill, int N)
{
    __shared__ float Wl[128 * 32];
    for (int i = threadIdx.x; i < 128 * 32; i += 256) Wl[i] = Wf[i];
    __syncthreads();

    const int gid = blockIdx.x * 256 + threadIdx.x;
    const int row = gid >> 3;          // one row per 8 threads
    const int dg  = gid & 7;           // dims 4*dg .. 4*dg+3
    if (row >= N) return;

    const float4* __restrict__ X4 = (const float4*)X + (size_t)row * 32;
    const float4* __restrict__ W4 = (const float4*)Wl;

    float4 acc = *(const float4*)(bf + 4 * dg);

    #pragma unroll 8
    for (int f4 = 0; f4 < 32; ++f4) {
        const float4 xv = X4[f4];
        if (f4 == 0 && dg == 0) skill[row] = (int)xv.x;  // trunc == astype(int32)
        const float4 w0 = W4[(4 * f4 + 0) * 8 + dg];
        const float4 w1 = W4[(4 * f4 + 1) * 8 + dg];
        const float4 w2 = W4[(4 * f4 + 2) * 8 + dg];
        const float4 w3 = W4[(4 * f4 + 3) * 8 + dg];
        acc.x = fmaf(xv.x, w0.x, acc.x);
        acc.y = fmaf(xv.x, w0.y, acc.y);
        acc.z = fmaf(xv.x, w0.z, acc.z);
        acc.w = fmaf(xv.x, w0.w, acc.w);
        acc.x = fmaf(xv.y, w1.x, acc.x);
        acc.y = fmaf(xv.y, w1.y, acc.y);
        acc.z = fmaf(xv.y, w1.z, acc.z);
        acc.w = fmaf(xv.y, w1.w, acc.w);
        acc.x = fmaf(xv.z, w2.x, acc.x);
        acc.y = fmaf(xv.z, w2.y, acc.y);
        acc.z = fmaf(xv.z, w2.z, acc.z);
        acc.w = fmaf(xv.z, w2.w, acc.w);
        acc.x = fmaf(xv.w, w3.x, acc.x);
        acc.y = fmaf(xv.w, w3.y, acc.y);
        acc.z = fmaf(xv.w, w3.z, acc.z);
        acc.w = fmaf(xv.w, w3.w, acc.w);
    }

    *(float4*)(feat + (size_t)row * 32 + 4 * dg) = acc;
}

// ---------------------------------------------------------------------------
// K2a: per-(b,l) row pipeline with 8 threads/row (dg = 4-dim quadrant).
// 102400 rows -> 819200 threads -> 12800 waves (~50/CU): gather latency
// hidden by TLP. Per thread: 5 feat float4 gathers + 5 skill gathers ->
// mean + struct-sim -> LayerNorm (shfl_xor reduce over the 8-lane group)
// -> broadcast full 32-d hist via shfl -> 4 outputs of hist @ Wgcn
// (Wgcn in LDS, b128 reads: 8 distinct addrs/wave -> conflict-free).
// xw written to ws [B*L, 32]: 1KB contiguous per wave store.
// ---------------------------------------------------------------------------
__global__ __launch_bounds__(256) void k_rows(
    const float* __restrict__ feat, const int* __restrict__ skill,
    const int* __restrict__ rnodes, const int* __restrict__ ridx,
    const int* __restrict__ dst_ids,
    const float* __restrict__ w_struct, const float* __restrict__ b_struct,
    const float* __restrict__ ln_g, const float* __restrict__ ln_b,
    const float* __restrict__ Wg, float* __restrict__ xw_out, int BL)
{
    __shared__ float Wgl[32 * 32];
    for (int i = threadIdx.x; i < 1024; i += 256) Wgl[i] = Wg[i];
    __syncthreads();

    const int rid = blockIdx.x * 32 + (threadIdx.x >> 3);
    if (rid >= BL) return;
    const int dg   = threadIdx.x & 7;
    const int lane = threadIdx.x & 63;
    const int b = rid / 100;
    const int l = rid - b * 100;

    const int* __restrict__ rb = ridx + b * 5;
    const int cskill = skill[dst_ids[b]];   // same addr across lanes of b: L1 broadcast

    float4 acc = f4zero();
    int simc = 0;
    #pragma unroll
    for (int r = 0; r < 5; ++r) {
        const int node = rnodes[(size_t)rb[r] * 100 + l];
        simc += (skill[node] == cskill) ? 1 : 0;
        const float4 v = *(const float4*)(feat + (size_t)node * 32 + 4 * dg);
        acc.x += v.x; acc.y += v.y; acc.z += v.z; acc.w += v.w;
    }

    const float simf = (float)simc * 0.2f;
    {
        const float4 ws = ((const float4*)w_struct)[dg];
        const float4 bs = ((const float4*)b_struct)[dg];
        acc.x = fmaf(acc.x, 0.2f, fmaf(simf, ws.x, bs.x));
        acc.y = fmaf(acc.y, 0.2f, fmaf(simf, ws.y, bs.y));
        acc.z = fmaf(acc.z, 0.2f, fmaf(simf, ws.z, bs.z));
        acc.w = fmaf(acc.w, 0.2f, fmaf(simf, ws.w, bs.w));
    }

    // LayerNorm over D=32 = 8 lanes x 4 dims (two-pass, biased var)
    float part = acc.x + acc.y + acc.z + acc.w;
    part += __shfl_xor(part, 1);
    part += __shfl_xor(part, 2);
    part += __shfl_xor(part, 4);
    const float mu = part * (1.f / 32.f);
    float dx, sq;
    dx = acc.x - mu; sq  = dx * dx;
    dx = acc.y - mu; sq  = fmaf(dx, dx, sq);
    dx = acc.z - mu; sq  = fmaf(dx, dx, sq);
    dx = acc.w - mu; sq  = fmaf(dx, dx, sq);
    sq += __shfl_xor(sq, 1);
    sq += __shfl_xor(sq, 2);
    sq += __shfl_xor(sq, 4);
    const float rs = rsqrtf(sq * (1.f / 32.f) + LN_EPS);

    float4 y;
    {
        const float4 g4 = ((const float4*)ln_g)[dg];
        const float4 b4 = ((const float4*)ln_b)[dg];
        y.x = fmaf((acc.x - mu) * rs, g4.x, b4.x);
        y.y = fmaf((acc.y - mu) * rs, g4.y, b4.y);
        y.z = fmaf((acc.z - mu) * rs, g4.z, b4.z);
        y.w = fmaf((acc.w - mu) * rs, g4.w, b4.w);
    }

    // broadcast full 32-dim hist across the 8-lane group
    float h[32];
    const int base = lane & ~7;
    #pragma unroll
    for (int s = 0; s < 8; ++s) {
        h[4 * s + 0] = __shfl(y.x, base + s, 64);
        h[4 * s + 1] = __shfl(y.y, base + s, 64);
        h[4 * s + 2] = __shfl(y.z, base + s, 64);
        h[4 * s + 3] = __shfl(y.w, base + s, 64);
    }

    // xw quadrant: xw[4dg+j] = sum_k h[k] * Wg[k][4dg+j]
    float4 o = f4zero();
    const float4* __restrict__ W4 = (const float4*)Wgl;
    #pragma unroll
    for (int k = 0; k < 32; ++k) {
        const float4 w = W4[k * 8 + dg];
        o.x = fmaf(h[k], w.x, o.x);
        o.y = fmaf(h[k], w.y, o.y);
        o.z = fmaf(h[k], w.z, o.z);
        o.w = fmaf(h[k], w.w, o.w);
    }

    *(float4*)(xw_out + (size_t)rid * 32 + 4 * dg) = o;
}

// ---------------------------------------------------------------------------
// K2b: per-sample tail. 1024 blocks x 128 threads. Loads xw[b] (sequential),
// valid via __syncthreads_count, chain-GCN via LDS xwT neighbor access,
// column-sum pooling, then 32x32 GEMVs for src_emb / dst_emb.
// ---------------------------------------------------------------------------
__global__ __launch_bounds__(128) void k_tail(
    const float* __restrict__ feat, const int* __restrict__ rnodes,
    const int* __restrict__ ridx, const int* __restrict__ dst_ids,
    const float* __restrict__ xw_in, const float* __restrict__ b_gcn,
    const float* __restrict__ Wo, const float* __restrict__ b_out,
    float* __restrict__ out, int B)
{
    __shared__ float Wol[32 * 32];
    __shared__ float xwT[32][100];
    __shared__ float pooled[32];
    __shared__ int   pidx0;

    const int t = threadIdx.x, b = blockIdx.x;

    for (int i = t; i < 1024; i += 128) Wol[i] = Wo[i];
    if (t == 0) pidx0 = ridx[b * 5];
    __syncthreads();

    const int l = t;
    const int node0 = (l < 100) ? rnodes[(size_t)pidx0 * 100 + l] : 0;
    const int valid = __syncthreads_count(node0 > 0);

    float4 xw[8];
    if (l < 100) {
        const float4* xp = (const float4*)(xw_in + ((size_t)b * 100 + l) * 32);
        #pragma unroll
        for (int q = 0; q < 8; ++q) {
            xw[q] = xp[q];
            xwT[4 * q + 0][l] = xw[q].x;
            xwT[4 * q + 1][l] = xw[q].y;
            xwT[4 * q + 2][l] = xw[q].z;
            xwT[4 * q + 3][l] = xw[q].w;
        }
    }
    __syncthreads();

    // chain-GCN: out[l] = xw[l]/deg[l] + edge(l-1->l)*xw[l-1]*rsqrt(deg[l-1]deg[l]);
    // gnn = relu(out + b_gcn). deg[0]=1; deg[v>=1] = 1 + (v < valid).
    if (l < 100) {
        const bool hm = (l >= 1) && (l < valid);
        const float degl  = 1.f + ((l >= 1 && l < valid) ? 1.f : 0.f);
        const float deglm = 1.f + ((l - 1 >= 1 && (l - 1) < valid) ? 1.f : 0.f);
        const float invd  = 1.f / degl;                    // deg in {1,2}: exact
        const float invn  = hm ? rsqrtf(deglm * degl) : 0.f;
        const int lm = hm ? (l - 1) : l;                   // safe LDS index when !hm
        #define GNN_D(D, C) { \
            const float m = hm ? xwT[D][lm] * invn : 0.f; \
            const float o = fmaf(xw[(D) / 4].C, invd, m) + bg4.C; \
            xw[(D) / 4].C = fmaxf(o, 0.f); }
        #pragma unroll
        for (int q = 0; q < 8; ++q) {
            const float4 bg4 = ((const float4*)b_gcn)[q];
            GNN_D(4 * q + 0, x) GNN_D(4 * q + 1, y)
            GNN_D(4 * q + 2, z) GNN_D(4 * q + 3, w)
        }
        #undef GNN_D
    }
    __syncthreads();   // all xwT reads done before overwrite (WAR)

    if (l < 100) {
        #pragma unroll
        for (int q = 0; q < 8; ++q) {
            xwT[4 * q + 0][l] = xw[q].x;
            xwT[4 * q + 1][l] = xw[q].y;
            xwT[4 * q + 2][l] = xw[q].z;
            xwT[4 * q + 3][l] = xw[q].w;
        }
    }
    __syncthreads();

    // global_mean_pool over L=100 (column sums; banks rotate per j: conflict-free)
    if (t < 32) {
        float s = 0.f;
        for (int j = 0; j < 100; ++j) s += xwT[t][j];
        pooled[t] = s * 0.01f;
    }
    __syncthreads();

    if (t < 32) {
        float s = b_out[t];
        #pragma unroll 8
        for (int k = 0; k < 32; ++k) s = fmaf(pooled[k], Wol[k * 32 + t], s);
        out[(size_t)b * 32 + t] = s;                       // src_emb
    } else if (t < 64) {
        const int d = t - 32;
        const float* fr = feat + (size_t)dst_ids[b] * 32;  // broadcast reads
        float s = b_out[d];
        #pragma unroll 8
        for (int k = 0; k < 32; ++k) s = fmaf(fr[k], Wol[k * 32 + d], s);
        out[(size_t)B * 32 + (size_t)b * 32 + d] = s;      // dst_emb
    }
}

// ---------------------------------------------------------------------------
extern "C" void kernel_launch(void* const* d_in, const int* in_sizes, int n_in,
                              void* d_out, int out_size, void* d_ws, size_t ws_size,
                              hipStream_t stream)
{
    const float* X      = (const float*)d_in[0];   // [N,128]
    const int*   rnodes = (const int*)  d_in[1];   // [P,100]
    const int*   ridx   = (const int*)  d_in[2];   // [B,5]
    /* d_in[3] src_node_ids: unused by reference */
    const int*   dst    = (const int*)  d_in[4];   // [B]
    /* d_in[5] node_interact_times: unused */
    const float* Wf  = (const float*)d_in[6];
    const float* bf  = (const float*)d_in[7];
    const float* wst = (const float*)d_in[8];
    const float* bst = (const float*)d_in[9];
    const float* lg  = (const float*)d_in[10];
    const float* lb  = (const float*)d_in[11];
    const float* Wg  = (const float*)d_in[12];
    const float* bg  = (const float*)d_in[13];
    const float* Wo  = (const float*)d_in[14];
    const float* bo  = (const float*)d_in[15];

    const int N = in_sizes[0] / 128;   // 100000
    const int B = in_sizes[4];         // 1024
    const int BL = B * 100;

    // workspace layout (all 16B-aligned):
    //   feat_all [N,32] f32 | skill [N] i32 (rounded to 16B) | xw [B*L,32] f32
    float* feat  = (float*)d_ws;
    int*   skill = (int*)((char*)d_ws + (size_t)N * 32 * sizeof(float));
    size_t skill_bytes = (((size_t)N * sizeof(int)) + 15) & ~(size_t)15;
    float* xw_ws = (float*)((char*)skill + skill_bytes);
    float* out   = (float*)d_out;

    k_feat<<<(N * 8 + 255) / 256, 256, 0, stream>>>(X, Wf, bf, feat, skill, N);
    k_rows<<<(BL * 8 + 255) / 256, 256, 0, stream>>>(feat, skill, rnodes, ridx, dst,
                                                     wst, bst, lg, lb, Wg, xw_ws, BL);
    k_tail<<<B, 128, 0, stream>>>(feat, rnodes, ridx, dst, xw_ws,
                                  bg, Wo, bo, out, B);
}